// Round 2
// baseline (1969.516 us; speedup 1.0000x reference)
//
#include <hip/hip_runtime.h>
#include <hip/hip_bf16.h>

// CATSCluster: fused 3-stream MLP (768->256->128) + combine on MI355X.
// R2: barrier-free wave-independent structure. Each wave owns 16 rows
// end-to-end (GEMM1 m-tile = wave's rows, all 16 n-tiles; H transpose via
// wave-private LDS; GEMM2 + combine wave-local). Numerics unchanged from R1:
// x=hi+lo, W=hi+lo, keep hh+hl+lh for GEMM1; H rounded to bf16; W2/W4 split;
// combine in fp32.

typedef short short8 __attribute__((ext_vector_type(8)));   // 8 x bf16
typedef float f32x4 __attribute__((ext_vector_type(4)));    // MFMA accumulator

// d_ws layout (unsigned short elements)
#define W1H_OFF 0u
#define W1L_OFF 196608u
#define W3H_OFF 393216u
#define W3L_OFF 589824u
#define W2H_OFF 786432u
#define W2L_OFF 819200u
#define W4H_OFF 851968u
#define W4L_OFF 884736u

__device__ __forceinline__ unsigned short bf16_rne(float f) {
  unsigned int u = __float_as_uint(f);
  u += 0x7FFFu + ((u >> 16) & 1u);      // round-to-nearest-even
  return (unsigned short)(u >> 16);
}

__device__ __forceinline__ void split_bf16(float f, unsigned short& h, unsigned short& l) {
  h = bf16_rne(f);
  float fh = __uint_as_float(((unsigned int)h) << 16);
  l = bf16_rne(f - fh);                 // |x - hi - lo| ~ 2^-18 |x|
}

__global__ __launch_bounds__(256) void prep_weights(
    const float* __restrict__ W1, const float* __restrict__ W2,
    const float* __restrict__ W3, const float* __restrict__ W4,
    unsigned short* __restrict__ ws)
{
  int i = blockIdx.x * 256 + threadIdx.x;
  if (i < 196608) {
    unsigned short h, l;
    split_bf16(W1[i], h, l); ws[W1H_OFF + i] = h; ws[W1L_OFF + i] = l;
    split_bf16(W3[i], h, l); ws[W3H_OFF + i] = h; ws[W3L_OFF + i] = l;
    if (i < 32768) {
      split_bf16(W2[i], h, l); ws[W2H_OFF + i] = h; ws[W2L_OFF + i] = l;
      split_bf16(W4[i], h, l); ws[W4H_OFF + i] = h; ws[W4L_OFF + i] = l;
    }
  }
}

__device__ __forceinline__ void split8(const float4 a, const float4 b, short8& h, short8& l) {
  float f[8] = {a.x, a.y, a.z, a.w, b.x, b.y, b.z, b.w};
#pragma unroll
  for (int j = 0; j < 8; ++j) {
    unsigned short hh, ll;
    split_bf16(f[j], hh, ll);
    h[j] = (short)hh; l[j] = (short)ll;
  }
}

#define STRIDE_H 264   // shorts/row: 528B, 16B-aligned; q-group offset 16 banks -> <=4-way on writes

__global__ __launch_bounds__(256) void catsc_main(
    const float* __restrict__ X, const unsigned short* __restrict__ ws,
    const float* __restrict__ W5, float* __restrict__ out)
{
  __shared__ short lsH[4][16 * STRIDE_H];   // wave-private transpose buffers, 33,792 B

  const int tid  = threadIdx.x;
  const int wave = tid >> 6;
  const int lane = tid & 63;
  const int l15  = lane & 15;
  const int q    = lane >> 4;
  const int blk  = blockIdx.x;              // 64 rows/block; 64 blocks per n

  // X_data is (16, 4097, 2304); skip row 0 of each n. This lane's row:
  const int row = (blk >> 6) * 4097 + 1 + ((blk & 63) << 6) + wave * 16 + l15;
  const float* Xrow = X + (size_t)row * 2304 + q * 8;   // k-base for this lane

  short* myH = &lsH[wave][0];

  f32x4 z1[8];   // s=0: relu(p1);  after s=1: |z(p1) - z(p2)|

#pragma unroll
  for (int s = 0; s < 3; ++s) {
    const int so = (s == 0) ? 768 : (s == 1 ? 1536 : 0);   // p1, p2, q
    const unsigned short* B1h = ws + (s == 2 ? W3H_OFF : W1H_OFF);
    const unsigned short* B1l = ws + (s == 2 ? W3L_OFF : W1L_OFF);
    const unsigned short* B2h = ws + (s == 2 ? W4H_OFF : W2H_OFF);
    const unsigned short* B2l = ws + (s == 2 ? W4L_OFF : W2L_OFF);

    f32x4 acc[16];
#pragma unroll
    for (int n = 0; n < 16; ++n) acc[n] = f32x4{0.f, 0.f, 0.f, 0.f};

    // ---- GEMM1: 64 rows x 768 -> 256, barrier-free, A from global ----
    for (int c = 0; c < 24; ++c) {
      const float* ap = Xrow + so + c * 32;
      float4 va = *(const float4*)(ap);
      float4 vb = *(const float4*)(ap + 4);
      short8 Ah, Al;
      split8(va, vb, Ah, Al);

#pragma unroll
      for (int half = 0; half < 2; ++half) {
        short8 Bh[8], Bl[8];
#pragma unroll
        for (int n = 0; n < 8; ++n) {
          size_t off = (size_t)(((half * 8 + n) * 16 + l15) * 768 + c * 32 + q * 8);
          Bh[n] = *(const short8*)(B1h + off);
          Bl[n] = *(const short8*)(B1l + off);
        }
#pragma unroll
        for (int n = 0; n < 8; ++n)
          acc[half * 8 + n] = __builtin_amdgcn_mfma_f32_16x16x32_bf16(Ah, Bh[n], acc[half * 8 + n], 0, 0, 0);
#pragma unroll
        for (int n = 0; n < 8; ++n)
          acc[half * 8 + n] = __builtin_amdgcn_mfma_f32_16x16x32_bf16(Ah, Bl[n], acc[half * 8 + n], 0, 0, 0);
#pragma unroll
        for (int n = 0; n < 8; ++n)
          acc[half * 8 + n] = __builtin_amdgcn_mfma_f32_16x16x32_bf16(Al, Bh[n], acc[half * 8 + n], 0, 0, 0);
      }
    }

    // ---- H = relu(acc) -> wave-private LDS as bf16 (no __syncthreads) ----
    // C-layout: row_local = q*4+i, col = n*16+l15  (rows are this wave's own)
#pragma unroll
    for (int n = 0; n < 16; ++n)
#pragma unroll
      for (int i = 0; i < 4; ++i)
        myH[(q * 4 + i) * STRIDE_H + n * 16 + l15] = (short)bf16_rne(fmaxf(acc[n][i], 0.f));

    // ---- GEMM2: 16 rows x 256 -> 128 (H bf16 x W split, 2 terms) ----
    f32x4 acc2[8];
#pragma unroll
    for (int n = 0; n < 8; ++n) acc2[n] = f32x4{0.f, 0.f, 0.f, 0.f};

    for (int c2 = 0; c2 < 8; ++c2) {
      short8 Ha = *(const short8*)&myH[l15 * STRIDE_H + c2 * 32 + q * 8];
      short8 Ch[8], Cl[8];
#pragma unroll
      for (int n2 = 0; n2 < 8; ++n2) {
        size_t off = (size_t)((n2 * 16 + l15) * 256 + c2 * 32 + q * 8);
        Ch[n2] = *(const short8*)(B2h + off);
        Cl[n2] = *(const short8*)(B2l + off);
      }
#pragma unroll
      for (int n2 = 0; n2 < 8; ++n2)
        acc2[n2] = __builtin_amdgcn_mfma_f32_16x16x32_bf16(Ha, Ch[n2], acc2[n2], 0, 0, 0);
#pragma unroll
      for (int n2 = 0; n2 < 8; ++n2)
        acc2[n2] = __builtin_amdgcn_mfma_f32_16x16x32_bf16(Ha, Cl[n2], acc2[n2], 0, 0, 0);
    }

    if (s == 0) {
#pragma unroll
      for (int n2 = 0; n2 < 8; ++n2)
#pragma unroll
        for (int i = 0; i < 4; ++i)
          z1[n2][i] = fmaxf(acc2[n2][i], 0.f);
    } else if (s == 1) {
      // fold: z1 = |z(p1) - z(p2)|, freeing 32 VGPRs for the q-stream
#pragma unroll
      for (int n2 = 0; n2 < 8; ++n2)
#pragma unroll
        for (int i = 0; i < 4; ++i)
          z1[n2][i] = fabsf(z1[n2][i] - fmaxf(acc2[n2][i], 0.f));
    } else {
      // ---- combine: out = tanh(relu(sum_o zq * |zp1-zp2| * W5[o])) ----
      float w5c[8];
#pragma unroll
      for (int n2 = 0; n2 < 8; ++n2) w5c[n2] = W5[n2 * 16 + l15];
#pragma unroll
      for (int i = 0; i < 4; ++i) {
        float v = 0.f;
#pragma unroll
        for (int n2 = 0; n2 < 8; ++n2)
          v += fmaxf(acc2[n2][i], 0.f) * z1[n2][i] * w5c[n2];
        // sum over the 16 cols held across l15 (xor stays within 16-lane group)
        v += __shfl_xor(v, 1);
        v += __shfl_xor(v, 2);
        v += __shfl_xor(v, 4);
        v += __shfl_xor(v, 8);
        if (l15 == 0)
          out[(size_t)blk * 64 + wave * 16 + q * 4 + i] = tanhf(fmaxf(v, 0.f));
      }
    }
  }
}

extern "C" void kernel_launch(void* const* d_in, const int* in_sizes, int n_in,
                              void* d_out, int out_size, void* d_ws, size_t ws_size,
                              hipStream_t stream) {
  const float* X  = (const float*)d_in[0];
  const float* W1 = (const float*)d_in[1];
  const float* W2 = (const float*)d_in[2];
  const float* W3 = (const float*)d_in[3];
  const float* W4 = (const float*)d_in[4];
  const float* W5 = (const float*)d_in[5];
  float* out = (float*)d_out;
  unsigned short* ws = (unsigned short*)d_ws;  // needs 1.75 MB

  prep_weights<<<dim3(768), dim3(256), 0, stream>>>(W1, W2, W3, W4, ws);
  catsc_main<<<dim3(1024), dim3(256), 0, stream>>>(X, ws, W5, out);
}